// Round 6
// baseline (222.606 us; speedup 1.0000x reference)
//
#include <hip/hip_runtime.h>
#include <hip/hip_bf16.h>

// Problem constants: B=8, N=128, D=512, L=48, 2 GCN layers.
//   t = einsum('ldk,bjk->bljd', w, h)  ==  T[(b*128+j), l*512+d] = sum_k H[bj,k]*Wflat[ld,k]
//   msg[b,i,d] = sum_j adj[b,i,j] * T[b*128+j, lab[b,i,j]*512+d];  h = relu(msg/(1+deg))
//   out = relu(relu(h@w0^T+b0)@w1^T+b1)
// Big GEMM (M=1024, N=24576, K=512): 256x256 8-phase template (T1+T2+T3+T4+T5).
// MLP via bf16 hi/lo compensation on the 128x128 2-phase kernel (small shapes).

typedef unsigned short u16;
typedef unsigned int u32;
using bf16x8 = __bf16 __attribute__((ext_vector_type(8)));
using f32x4 = float __attribute__((ext_vector_type(4)));

__device__ __forceinline__ u16 f2bf(float f) {
  u32 u = __float_as_uint(f);
  u32 r = u + 0x7fffu + ((u >> 16) & 1u);   // round-to-nearest-even
  return (u16)(r >> 16);
}
__device__ __forceinline__ float bf2f(u16 h) {
  return __uint_as_float(((u32)h) << 16);
}

__device__ __forceinline__ void gl_lds16(const u16* g, u16* l) {
  __builtin_amdgcn_global_load_lds(
      (const __attribute__((address_space(1))) u32*)g,
      (__attribute__((address_space(3))) u32*)l, 16, 0, 0);
}

// phase bracket: {barrier; lgkmcnt(0); sched_barrier; setprio(1)} ... {setprio(0); sched_barrier; barrier}
__device__ __forceinline__ void ph_begin() {
  __builtin_amdgcn_s_barrier();
  asm volatile("s_waitcnt lgkmcnt(0)" ::: "memory");
  __builtin_amdgcn_sched_barrier(0);
  __builtin_amdgcn_s_setprio(1);
}
__device__ __forceinline__ void ph_end() {
  __builtin_amdgcn_s_setprio(0);
  __builtin_amdgcn_sched_barrier(0);
  __builtin_amdgcn_s_barrier();
}

// ---------------- fp32 -> bf16 conversion (float4 vectorized) ----------------
__global__ __launch_bounds__(256)
void cvt_f32_bf16(const float* __restrict__ in, u16* __restrict__ out, int n4) {
  int stride = gridDim.x * blockDim.x;
  for (int i = blockIdx.x * blockDim.x + threadIdx.x; i < n4; i += stride) {
    float4 v = ((const float4*)in)[i];
    uint2 o;
    o.x = (u32)f2bf(v.x) | ((u32)f2bf(v.y) << 16);
    o.y = (u32)f2bf(v.z) | ((u32)f2bf(v.w) << 16);
    ((uint2*)out)[i] = o;
  }
}

// ---------------- MLP weight prep: hi/lo split into concatenated-K layout ----
__global__ __launch_bounds__(256)
void prep_mlp_w(const float* __restrict__ w0, const float* __restrict__ w1,
                u16* __restrict__ Bp1, u16* __restrict__ Bp2) {
  int idx = blockIdx.x * 256 + threadIdx.x;   // grid covers 2*262144
  if (idx < 262144) {
    const int n = idx >> 9, k = idx & 511;
    const float v = w0[idx];
    const u16 hi = f2bf(v);
    const float lo = v - bf2f(hi);
    Bp1[n * 1024 + k] = hi;
    Bp1[n * 1024 + 512 + k] = f2bf(lo);
  } else {
    const int j = idx - 262144;
    const int n = j >> 9, k = j & 511;
    const float v = w1[j];
    const u16 hi = f2bf(v);
    const float lo = v - bf2f(hi);
    Bp2[n * 1536 + k] = hi;
    Bp2[n * 1536 + 512 + k] = f2bf(lo);
    Bp2[n * 1536 + 1024 + k] = hi;
  }
}

// ================= 256x256 8-phase bf16 NT GEMM (big einsum) =================
// C[m,n] = sum_k A[m,k]*B[n,k]; A: MxK, B: NxK, C bf16 MxN (ldc=N).
// 512 thr = 8 waves (2M x 4N); wave owns 128x64; BK=64; LDS 128 KiB dbuf.
// XOR swizzle: LDS(row, cu) holds global (row, cu ^ (row&7)) 16B units
// (linear gl_lds dest + inverse-swizzled global source; ds_read applies XOR).
__global__ __launch_bounds__(512, 2)
void gemm256_8ph(const u16* __restrict__ A, const u16* __restrict__ B,
                 u16* __restrict__ C, int N, int K) {
  __shared__ u16 sA[2][256 * 64];   // 32 KB per buffer
  __shared__ u16 sB[2][256 * 64];

  const int tid = threadIdx.x;
  const int lane = tid & 63;
  const int wid = tid >> 6;        // 0..7
  const int wm = wid >> 2;         // 0..1  (m-half of tile)
  const int wn = wid & 3;          // 0..3  (n-quarter of tile)

  // XCD-aware bijective swizzle (gridDim.x % 8 == 0)
  const int nwg = gridDim.x;
  const int cpx = nwg >> 3;
  const int swz = (blockIdx.x & 7) * cpx + (blockIdx.x >> 3);
  const int ntc = N >> 8;          // tile-cols
  const int m0 = (swz / ntc) * 256;
  const int n0 = (swz % ntc) * 256;

  // staging: thread t -> 16B unit; row = q*64 + (t>>3); src col unit inverse-swizzled
  const int srow = tid >> 3;                         // 0..63
  const int sc = ((tid & 7) ^ (srow & 7)) * 8;       // k-elem offset (swizzled src)
  const u16* gA = A + (size_t)(m0 + srow) * K + sc;
  const u16* gB = B + (size_t)(n0 + srow) * K + sc;

  auto stA = [&](int buf, int kt, int q) {
    gl_lds16(gA + (size_t)(q * 64) * K + kt * 64, &sA[buf][q * 4096 + tid * 8]);
  };
  auto stB = [&](int buf, int kt, int q) {
    gl_lds16(gB + (size_t)(q * 64) * K + kt * 64, &sB[buf][q * 4096 + tid * 8]);
  };

  // frag read addressing (16x16x32 MFMA, proven layout)
  const int r15 = lane & 15;
  const int hi4 = lane >> 4;        // 0..3
  const int xk = r15 & 7;
  const int ck0 = ((0 * 4 + hi4) ^ xk) * 8;   // k-sub 0 col (elems, swizzled)
  const int ck1 = ((1 * 4 + hi4) ^ xk) * 8;   // k-sub 1
  const int rowA = wm * 128 + r15;  // + mh*64 + mi*16
  const int rowB = wn * 64 + r15;   // + ni*16

  f32x4 acc[8][4];
#pragma unroll
  for (int i = 0; i < 8; ++i)
#pragma unroll
    for (int j = 0; j < 4; ++j)
      acc[i][j] = (f32x4){0.f, 0.f, 0.f, 0.f};

  const int NT = K / 64;            // 8 for K=512

  // prologue: stage kt0 + kt1 (8 gl_lds each, per-wave vmcnt counts its own)
#pragma unroll
  for (int q = 0; q < 4; ++q) stA(0, 0, q);
#pragma unroll
  for (int q = 0; q < 4; ++q) stB(0, 0, q);
#pragma unroll
  for (int q = 0; q < 4; ++q) stA(1, 1, q);
#pragma unroll
  for (int q = 0; q < 4; ++q) stB(1, 1, q);
  asm volatile("s_waitcnt vmcnt(8)" ::: "memory");   // kt0 landed; kt1 in flight
  __builtin_amdgcn_s_barrier();

  bf16x8 af[4][2], bfr[4][2];

  for (int kt = 0; kt < NT; ++kt) {
    const int buf = kt & 1;
    const bool st = (kt + 2 < NT);

    // ---- P1: read A(mh=0) + B(ni=0,1); MFMA Q(0,0) ----
#pragma unroll
    for (int mi = 0; mi < 4; ++mi) {
      af[mi][0] = *(const bf16x8*)&sA[buf][(rowA + mi * 16) * 64 + ck0];
      af[mi][1] = *(const bf16x8*)&sA[buf][(rowA + mi * 16) * 64 + ck1];
    }
#pragma unroll
    for (int ni = 0; ni < 2; ++ni) {
      bfr[ni][0] = *(const bf16x8*)&sB[buf][(rowB + ni * 16) * 64 + ck0];
      bfr[ni][1] = *(const bf16x8*)&sB[buf][(rowB + ni * 16) * 64 + ck1];
    }
    ph_begin();
#pragma unroll
    for (int mi = 0; mi < 4; ++mi)
#pragma unroll
      for (int ni = 0; ni < 2; ++ni)
#pragma unroll
        for (int ks = 0; ks < 2; ++ks)
          acc[mi][ni] = __builtin_amdgcn_mfma_f32_16x16x32_bf16(
              af[mi][ks], bfr[ni][ks], acc[mi][ni], 0, 0, 0);
    ph_end();

    // ---- P2: read B(ni=2,3); stage A-quarters 0,2 of kt+2; MFMA Q(0,1) ----
#pragma unroll
    for (int ni = 2; ni < 4; ++ni) {
      bfr[ni][0] = *(const bf16x8*)&sB[buf][(rowB + ni * 16) * 64 + ck0];
      bfr[ni][1] = *(const bf16x8*)&sB[buf][(rowB + ni * 16) * 64 + ck1];
    }
    if (st) { stA(buf, kt + 2, 0); stA(buf, kt + 2, 2); }
    ph_begin();
#pragma unroll
    for (int mi = 0; mi < 4; ++mi)
#pragma unroll
      for (int ni = 2; ni < 4; ++ni)
#pragma unroll
        for (int ks = 0; ks < 2; ++ks)
          acc[mi][ni] = __builtin_amdgcn_mfma_f32_16x16x32_bf16(
              af[mi][ks], bfr[ni][ks], acc[mi][ni], 0, 0, 0);
    ph_end();

    // ---- P3: read A(mh=1); stage all B-quarters of kt+2; MFMA Q(1,1) ----
#pragma unroll
    for (int mi = 0; mi < 4; ++mi) {
      af[mi][0] = *(const bf16x8*)&sA[buf][(rowA + 64 + mi * 16) * 64 + ck0];
      af[mi][1] = *(const bf16x8*)&sA[buf][(rowA + 64 + mi * 16) * 64 + ck1];
    }
    if (st) { stB(buf, kt + 2, 0); stB(buf, kt + 2, 1);
              stB(buf, kt + 2, 2); stB(buf, kt + 2, 3); }
    ph_begin();
#pragma unroll
    for (int mi = 0; mi < 4; ++mi)
#pragma unroll
      for (int ni = 2; ni < 4; ++ni)
#pragma unroll
        for (int ks = 0; ks < 2; ++ks)
          acc[4 + mi][ni] = __builtin_amdgcn_mfma_f32_16x16x32_bf16(
              af[mi][ks], bfr[ni][ks], acc[4 + mi][ni], 0, 0, 0);
    ph_end();

    // ---- P4: stage A-quarters 1,3 of kt+2; MFMA Q(1,0); counted vmcnt ----
    if (st) { stA(buf, kt + 2, 1); stA(buf, kt + 2, 3); }
    __builtin_amdgcn_s_barrier();
    __builtin_amdgcn_s_setprio(1);
#pragma unroll
    for (int mi = 0; mi < 4; ++mi)
#pragma unroll
      for (int ni = 0; ni < 2; ++ni)
#pragma unroll
        for (int ks = 0; ks < 2; ++ks)
          acc[4 + mi][ni] = __builtin_amdgcn_mfma_f32_16x16x32_bf16(
              af[mi][ks], bfr[ni][ks], acc[4 + mi][ni], 0, 0, 0);
    __builtin_amdgcn_s_setprio(0);
    __builtin_amdgcn_sched_barrier(0);
    if (kt + 1 < NT) {
      if (st) asm volatile("s_waitcnt vmcnt(8)" ::: "memory");  // kt+1 landed
      else    asm volatile("s_waitcnt vmcnt(0)" ::: "memory");  // pipeline drain
      __builtin_amdgcn_s_barrier();
    }
  }

  // epilogue: C/D layout col=lane&15, row=(lane>>4)*4+reg
  const int rq = hi4 * 4;
#pragma unroll
  for (int MI = 0; MI < 8; ++MI) {
#pragma unroll
    for (int ni = 0; ni < 4; ++ni) {
      const int row = m0 + wm * 128 + MI * 16 + rq;
      const int col = n0 + wn * 64 + ni * 16 + r15;
      f32x4 v = acc[MI][ni];
#pragma unroll
      for (int r = 0; r < 4; ++r)
        C[(size_t)(row + r) * N + col] = f2bf(v[r]);
    }
  }
}

// ============= 128x128 2-phase bf16 NT GEMM (small MLP shapes) ==============
// EPI 1: relu(acc+bias) -> hi/lo split (hi@col, hi@512+col, lo@1024+col), ldc=1536
// EPI 2: relu(acc+bias) -> fp32 store, ldc = N
#define BM 128
#define BN 128
#define BK 32

template <int EPI>
__global__ __launch_bounds__(256)
void gemm_nt_bf16(const u16* __restrict__ A, const u16* __restrict__ B,
                  void* __restrict__ C, const float* __restrict__ bias,
                  int N, int K, int ldc) {
  __shared__ u16 sA[2][BM * BK];
  __shared__ u16 sB[2][BN * BK];
  const int tid = threadIdx.x;
  const int lane = tid & 63;
  const int wid = tid >> 6;
  const int wm = wid >> 1;
  const int wn = wid & 1;
  const int m0 = blockIdx.y * BM;
  const int n0 = blockIdx.x * BN;

  const int srow = tid >> 2;
  const int scol = (tid & 3) * 8;
  const u16* gA0 = A + (size_t)(m0 + srow) * K + scol;
  const u16* gA1 = A + (size_t)(m0 + 64 + srow) * K + scol;
  const u16* gB0 = B + (size_t)(n0 + srow) * K + scol;
  const u16* gB1 = B + (size_t)(n0 + 64 + srow) * K + scol;

  auto stage = [&](int buf, int kt) {
    const int ko = kt * BK;
    gl_lds16(gA0 + ko, &sA[buf][tid * 8]);
    gl_lds16(gA1 + ko, &sA[buf][2048 + tid * 8]);
    gl_lds16(gB0 + ko, &sB[buf][tid * 8]);
    gl_lds16(gB1 + ko, &sB[buf][2048 + tid * 8]);
  };

  f32x4 acc[4][4];
#pragma unroll
  for (int i = 0; i < 4; ++i)
#pragma unroll
    for (int j = 0; j < 4; ++j)
      acc[i][j] = (f32x4){0.f, 0.f, 0.f, 0.f};

  const int NT = K / BK;
  stage(0, 0);
  asm volatile("s_waitcnt vmcnt(0)" ::: "memory");
  __syncthreads();

  const int r15 = lane & 15;
  const int ksub = (lane >> 4) * 8;
  int cur = 0;
  for (int kt = 0; kt < NT; ++kt) {
    if (kt + 1 < NT) stage(cur ^ 1, kt + 1);

    bf16x8 af[4], bfr[4];
#pragma unroll
    for (int mi = 0; mi < 4; ++mi)
      af[mi] = *(const bf16x8*)&sA[cur][(wm * 64 + mi * 16 + r15) * BK + ksub];
#pragma unroll
    for (int ni = 0; ni < 4; ++ni)
      bfr[ni] = *(const bf16x8*)&sB[cur][(wn * 64 + ni * 16 + r15) * BK + ksub];

#pragma unroll
    for (int mi = 0; mi < 4; ++mi)
#pragma unroll
      for (int ni = 0; ni < 4; ++ni)
        acc[mi][ni] = __builtin_amdgcn_mfma_f32_16x16x32_bf16(
            af[mi], bfr[ni], acc[mi][ni], 0, 0, 0);

    asm volatile("s_waitcnt vmcnt(0)" ::: "memory");
    __syncthreads();
    cur ^= 1;
  }

  const int rq = (lane >> 4) * 4;
#pragma unroll
  for (int mi = 0; mi < 4; ++mi) {
#pragma unroll
    for (int ni = 0; ni < 4; ++ni) {
      const int row = m0 + wm * 64 + mi * 16 + rq;
      const int col = n0 + wn * 64 + ni * 16 + r15;
      f32x4 v = acc[mi][ni];
      if (EPI == 1) {
        u16* Cb = (u16*)C;
        const float bv = bias[col];
#pragma unroll
        for (int r = 0; r < 4; ++r) {
          const float x = fmaxf(v[r] + bv, 0.0f);
          const u16 hi = f2bf(x);
          const float lo = x - bf2f(hi);
          const size_t base = (size_t)(row + r) * 1536 + col;
          Cb[base] = hi;
          Cb[base + 512] = hi;
          Cb[base + 1024] = f2bf(lo);
        }
      } else {
        float* Cf = (float*)C;
        const float bv = bias[col];
#pragma unroll
        for (int r = 0; r < 4; ++r)
          Cf[(size_t)(row + r) * ldc + col] = fmaxf(v[r] + bv, 0.0f);
      }
    }
  }
}

// ---------------- per-row gather-reduce: msg + relu(msg/denom) -> bf16 -------
// block = (b,i); skips adj==0 edges (branch is coherent; identical FP result
// since the skipped terms added exactly 0.0).
template <bool DUP>
__global__ __launch_bounds__(256)
void gcn_agg(const u16* __restrict__ T, const float* __restrict__ adj,
             const int* __restrict__ lab, u16* __restrict__ Hout) {
  const int bi = blockIdx.x;
  const int b = bi >> 7;
  const int tid = threadIdx.x;
  __shared__ float s_adj[128];
  __shared__ int s_off[128];
  if (tid < 128) {
    s_adj[tid] = adj[(size_t)bi * 128 + tid];
    const int lv = lab[(size_t)bi * 128 + tid];
    s_off[tid] = ((b * 128 + tid) * 48 + lv) * 512;
  }
  __syncthreads();

  const int d = tid * 2;
  float den = 1.0f, a0 = 0.f, a1 = 0.f;
#pragma unroll 4
  for (int j = 0; j < 128; ++j) {
    const float a = s_adj[j];
    if (a != 0.0f) {              // block-coherent branch; a is exactly 1.0
      den += 1.0f;
      const u32 u = *(const u32*)&T[(size_t)s_off[j] + d];
      a0 += __uint_as_float((u & 0xffffu) << 16);
      a1 += __uint_as_float(u & 0xffff0000u);
    }
  }
  const float r = 1.0f / den;
  a0 = fmaxf(a0 * r, 0.0f);
  a1 = fmaxf(a1 * r, 0.0f);
  const u32 o = (u32)f2bf(a0) | ((u32)f2bf(a1) << 16);
  if (DUP) {
    *(u32*)&Hout[(size_t)bi * 1024 + d] = o;
    *(u32*)&Hout[(size_t)bi * 1024 + 512 + d] = o;
  } else {
    *(u32*)&Hout[(size_t)bi * 512 + d] = o;
  }
}

// ---------------------------------------------------------------------------
extern "C" void kernel_launch(void* const* d_in, const int* in_sizes, int n_in,
                              void* d_out, int out_size, void* d_ws, size_t ws_size,
                              hipStream_t stream) {
  const float* gcn_inputs = (const float*)d_in[0];
  // d_in[1] = word_seq_len: unused by the reference
  const float* adj = (const float*)d_in[2];
  const int* lab = (const int*)d_in[3];
  const float* w_params = (const float*)d_in[4];
  const float* w0 = (const float*)d_in[5];
  const float* b0 = (const float*)d_in[6];
  const float* w1 = (const float*)d_in[7];
  const float* b1 = (const float*)d_in[8];
  float* out = (float*)d_out;

  // workspace layout (bytes):
  //   Wbf  [0,        25165824)  : 48*512*512 bf16
  //   T    [25165824, 75497472)  : 1024 x 24576 bf16
  //     Bp1 = T+0      (512x1024 bf16)  } written AFTER last T read
  //     Bp2 = T+1MB    (512x1536 bf16)  }
  //   Ha   [75497472, +1MB) : 1024x512 bf16
  //   Hb   [76546048, +1MB) : 1024x512 bf16
  //   Ap1  [77594624, +2MB) : 1024x1024 bf16 (agg#2 DUP output)
  //   Ap2  [79691776, +3MB) : 1024x1536 bf16 (MLP1 hi/hi/lo output)
  char* ws = (char*)d_ws;
  u16* Wbf = (u16*)ws;
  u16* T = (u16*)(ws + 25165824);
  u16* Bp1 = T;
  u16* Bp2 = (u16*)(ws + 25165824 + (1 << 20));
  u16* Ha = (u16*)(ws + 75497472);
  u16* Hb = (u16*)(ws + 76546048);
  u16* Ap1 = (u16*)(ws + 77594624);
  u16* Ap2 = (u16*)(ws + 79691776);

  cvt_f32_bf16<<<2048, 256, 0, stream>>>(w_params, Wbf, (48 * 512 * 512) / 4);
  cvt_f32_bf16<<<512, 256, 0, stream>>>(gcn_inputs, Ha, (8 * 128 * 512) / 4);

  // big einsum GEMM: M=1024, N=24576, K=512 -> 4x96 = 384 tiles (384%8==0)
  // GCN layer 1
  gemm256_8ph<<<384, 512, 0, stream>>>(Ha, Wbf, T, 24576, 512);
  gcn_agg<false><<<1024, 256, 0, stream>>>(T, adj, lab, Hb);
  // GCN layer 2
  gemm256_8ph<<<384, 512, 0, stream>>>(Hb, Wbf, T, 24576, 512);
  gcn_agg<true><<<1024, 256, 0, stream>>>(T, adj, lab, Ap1);   // -> A'=[H,H]

  // MLP weight hi/lo prep (T region dead now; Bp1/Bp2 alias it)
  prep_mlp_w<<<2048, 256, 0, stream>>>(w0, w1, Bp1, Bp2);

  // MLP layer 1: X1 = relu(Ha@W0^T+b0) as [X1hi, X1hi, X1lo] (K'=1536)
  dim3 gm(512 / BN, 1024 / BM);     // (4, 8)
  gemm_nt_bf16<1><<<gm, 256, 0, stream>>>(Ap1, Bp1, Ap2, b0, 512, 1024, 1536);
  // MLP layer 2: out = relu(X1@W1^T+b1), fp32
  gemm_nt_bf16<2><<<gm, 256, 0, stream>>>(Ap2, Bp2, out, b1, 512, 1536, 512);
}

// Round 7
// 174.735 us; speedup vs baseline: 1.2740x; 1.2740x over previous
//
#include <hip/hip_runtime.h>
#include <hip/hip_bf16.h>

// Problem constants: B=8, N=128, D=512, L=48, 2 GCN layers.
//   t = einsum('ldk,bjk->bljd', w, h)  ==  T[(b*128+j), l*512+d] = sum_k H[bj,k]*Wflat[ld,k]
//   msg[b,i,d] = sum_j adj[b,i,j] * T[b*128+j, lab[b,i,j]*512+d];  h = relu(msg/(1+deg))
//   out = relu(relu(h@w0^T+b0)@w1^T+b1)
// Big GEMM: proven 2-phase 128x128 MFMA kernel (47.5us measured) + XCD L2-band map.
// MLP: bf16 hi/lo compensation, split-K (deterministic fixed-order combine).

typedef unsigned short u16;
typedef unsigned int u32;
using bf16x8 = __bf16 __attribute__((ext_vector_type(8)));
using f32x4 = float __attribute__((ext_vector_type(4)));

__device__ __forceinline__ u16 f2bf(float f) {
  u32 u = __float_as_uint(f);
  u32 r = u + 0x7fffu + ((u >> 16) & 1u);   // round-to-nearest-even
  return (u16)(r >> 16);
}
__device__ __forceinline__ float bf2f(u16 h) {
  return __uint_as_float(((u32)h) << 16);
}

__device__ __forceinline__ void gl_lds16(const u16* g, u16* l) {
  __builtin_amdgcn_global_load_lds(
      (const __attribute__((address_space(1))) u32*)g,
      (__attribute__((address_space(3))) u32*)l, 16, 0, 0);
}

// ---------------- fp32 -> bf16 conversion (float4 vectorized) ----------------
__global__ __launch_bounds__(256)
void cvt_f32_bf16(const float* __restrict__ in, u16* __restrict__ out, int n4) {
  int stride = gridDim.x * blockDim.x;
  for (int i = blockIdx.x * blockDim.x + threadIdx.x; i < n4; i += stride) {
    float4 v = ((const float4*)in)[i];
    uint2 o;
    o.x = (u32)f2bf(v.x) | ((u32)f2bf(v.y) << 16);
    o.y = (u32)f2bf(v.z) | ((u32)f2bf(v.w) << 16);
    ((uint2*)out)[i] = o;
  }
}

// ---------------- MLP weight prep: hi/lo split into concatenated-K layout ----
// w0 (512x512 f32) -> Bp1 (512x1024 bf16): [n,k]=hi, [n,512+k]=lo
// w1 (512x512 f32) -> Bp2 (512x1536 bf16): [n,k]=hi, [n,512+k]=lo, [n,1024+k]=hi
__global__ __launch_bounds__(256)
void prep_mlp_w(const float* __restrict__ w0, const float* __restrict__ w1,
                u16* __restrict__ Bp1, u16* __restrict__ Bp2) {
  int idx = blockIdx.x * 256 + threadIdx.x;   // grid covers 2*262144
  if (idx < 262144) {
    const int n = idx >> 9, k = idx & 511;
    const float v = w0[idx];
    const u16 hi = f2bf(v);
    const float lo = v - bf2f(hi);
    Bp1[n * 1024 + k] = hi;
    Bp1[n * 1024 + 512 + k] = f2bf(lo);
  } else {
    const int j = idx - 262144;
    const int n = j >> 9, k = j & 511;
    const float v = w1[j];
    const u16 hi = f2bf(v);
    const float lo = v - bf2f(hi);
    Bp2[n * 1536 + k] = hi;
    Bp2[n * 1536 + 512 + k] = f2bf(lo);
    Bp2[n * 1536 + 1024 + k] = hi;
  }
}

// ---------------- bf16 NT GEMM: C[m,n] = sum_k A[m,k]*B[n,k] ----------------
// A: MxK row-major bf16, B: NxK row-major bf16.
// 128x128 tile, BK=32, 256 threads (4 waves, 2x2), 16x16x32 MFMA, 4x4 frags/wave.
// MODE 0: big einsum. 1-D grid 1536; XCD band map (XCD x owns n-tiles
//         [24x,24x+24) x 8 m-tiles -> B band 3.1MB fits per-XCD L2). bf16 C.
// MODE 1: split-K partial. 3-D grid (N/128, M/128, S); K-chunk = KC;
//         fp32 partial store at C + z*1024*N (combined later, fixed order).
#define BM 128
#define BN 128
#define BK 32

template <int MODE>
__global__ __launch_bounds__(256)
void gemm_nt_bf16(const u16* __restrict__ A, const u16* __restrict__ B,
                  void* __restrict__ C, int N, int K, int KC) {
  __shared__ u16 sA[2][BM * BK];
  __shared__ u16 sB[2][BN * BK];
  const int tid = threadIdx.x;
  const int lane = tid & 63;
  const int wid = tid >> 6;
  const int wm = wid >> 1;
  const int wn = wid & 1;

  int m0, n0, kc;
  if (MODE == 0) {
    // dispatch round-robins consecutive blockIdx across XCDs: XCD = bid % 8.
    // bid = r*8 + xcd -> XCD xcd gets r = 0..191: mt = r&7, n-band slot r>>3.
    const int bid = blockIdx.x;
    const int xcd = bid & 7;
    const int r = bid >> 3;
    m0 = (r & 7) * BM;                  // 8 m-tiles (M=1024)
    n0 = (xcd * 24 + (r >> 3)) * BN;    // 24 n-tiles per XCD band (N=24576)
    kc = 0;
  } else {
    m0 = blockIdx.y * BM;
    n0 = blockIdx.x * BN;
    kc = blockIdx.z;
  }

  const int srow = tid >> 2;
  const int scol = (tid & 3) * 8;
  const u16* gA0 = A + (size_t)(m0 + srow) * K + kc * KC + scol;
  const u16* gA1 = A + (size_t)(m0 + 64 + srow) * K + kc * KC + scol;
  const u16* gB0 = B + (size_t)(n0 + srow) * K + kc * KC + scol;
  const u16* gB1 = B + (size_t)(n0 + 64 + srow) * K + kc * KC + scol;

  auto stage = [&](int buf, int kt) {
    const int ko = kt * BK;
    gl_lds16(gA0 + ko, &sA[buf][tid * 8]);
    gl_lds16(gA1 + ko, &sA[buf][2048 + tid * 8]);
    gl_lds16(gB0 + ko, &sB[buf][tid * 8]);
    gl_lds16(gB1 + ko, &sB[buf][2048 + tid * 8]);
  };

  f32x4 acc[4][4];
#pragma unroll
  for (int i = 0; i < 4; ++i)
#pragma unroll
    for (int j = 0; j < 4; ++j)
      acc[i][j] = (f32x4){0.f, 0.f, 0.f, 0.f};

  const int NT = KC / BK;
  stage(0, 0);
  asm volatile("s_waitcnt vmcnt(0)" ::: "memory");
  __syncthreads();

  const int r15 = lane & 15;
  const int ksub = (lane >> 4) * 8;
  int cur = 0;
  for (int kt = 0; kt < NT; ++kt) {
    if (kt + 1 < NT) stage(cur ^ 1, kt + 1);   // prefetch next K-tile

    bf16x8 af[4], bfr[4];
#pragma unroll
    for (int mi = 0; mi < 4; ++mi)
      af[mi] = *(const bf16x8*)&sA[cur][(wm * 64 + mi * 16 + r15) * BK + ksub];
#pragma unroll
    for (int ni = 0; ni < 4; ++ni)
      bfr[ni] = *(const bf16x8*)&sB[cur][(wn * 64 + ni * 16 + r15) * BK + ksub];

#pragma unroll
    for (int mi = 0; mi < 4; ++mi)
#pragma unroll
      for (int ni = 0; ni < 4; ++ni)
        acc[mi][ni] = __builtin_amdgcn_mfma_f32_16x16x32_bf16(
            af[mi], bfr[ni], acc[mi][ni], 0, 0, 0);

    asm volatile("s_waitcnt vmcnt(0)" ::: "memory");
    __syncthreads();
    cur ^= 1;
  }

  // epilogue: C/D layout col=lane&15, row=(lane>>4)*4+reg  [m89-verified]
  const int rq = (lane >> 4) * 4;
#pragma unroll
  for (int mi = 0; mi < 4; ++mi) {
#pragma unroll
    for (int ni = 0; ni < 4; ++ni) {
      const int row = m0 + wm * 64 + mi * 16 + rq;
      const int col = n0 + wn * 64 + ni * 16 + r15;
      f32x4 v = acc[mi][ni];
      if (MODE == 0) {
        u16* Cb = (u16*)C;
        const size_t base = (size_t)row * N + col;
#pragma unroll
        for (int r = 0; r < 4; ++r)
          Cb[base + (size_t)r * N] = f2bf(v[r]);
      } else {
        float* Cf = (float*)C + (size_t)kc * 1024 * N;
#pragma unroll
        for (int r = 0; r < 4; ++r)
          Cf[(size_t)(row + r) * N + col] = v[r];
      }
    }
  }
}

// ---------------- per-row gather-reduce: msg + relu(msg/denom) -> bf16 -------
// block -> (b,i) with b = bid&7 so each XCD's L2 holds mostly one b's T slice.
// Skips adj==0 edges (bit-exact: skipped terms added exactly 0.0).
template <bool DUP>
__global__ __launch_bounds__(256)
void gcn_agg(const u16* __restrict__ T, const float* __restrict__ adj,
             const int* __restrict__ lab, u16* __restrict__ Hout) {
  const int bid = blockIdx.x;
  const int b = bid & 7;
  const int i = bid >> 3;
  const int bi = b * 128 + i;
  const int tid = threadIdx.x;
  __shared__ float s_adj[128];
  __shared__ int s_off[128];
  if (tid < 128) {
    s_adj[tid] = adj[(size_t)bi * 128 + tid];
    const int lv = lab[(size_t)bi * 128 + tid];
    s_off[tid] = ((b * 128 + tid) * 48 + lv) * 512;
  }
  __syncthreads();

  const int d = tid * 2;
  float den = 1.0f, a0 = 0.f, a1 = 0.f;
#pragma unroll 4
  for (int j = 0; j < 128; ++j) {
    const float a = s_adj[j];
    if (a != 0.0f) {              // block-uniform branch; a is exactly 1.0
      den += 1.0f;
      const u32 u = *(const u32*)&T[(size_t)s_off[j] + d];
      a0 += __uint_as_float((u & 0xffffu) << 16);
      a1 += __uint_as_float(u & 0xffff0000u);
    }
  }
  const float r = 1.0f / den;
  a0 = fmaxf(a0 * r, 0.0f);
  a1 = fmaxf(a1 * r, 0.0f);
  const u32 o = (u32)f2bf(a0) | ((u32)f2bf(a1) << 16);
  if (DUP) {
    *(u32*)&Hout[(size_t)bi * 1024 + d] = o;
    *(u32*)&Hout[(size_t)bi * 1024 + 512 + d] = o;
  } else {
    *(u32*)&Hout[(size_t)bi * 512 + d] = o;
  }
}

// ---------------- split-K combines (fixed ascending order -> deterministic) --
// MLP1: sum 4 partials + bias, relu, hi/lo split -> Ap2 [hi, hi, lo] (1536-wide)
__global__ __launch_bounds__(256)
void combine_mlp1(const float* __restrict__ P, const float* __restrict__ bias,
                  u16* __restrict__ Ap2) {
  const int idx = blockIdx.x * 256 + threadIdx.x;   // 262144 = 1024*512/2
  const int m = idx >> 8;
  const int n = (idx & 255) * 2;
  float s0 = 0.f, s1 = 0.f;
#pragma unroll
  for (int s = 0; s < 4; ++s) {
    const float2 v = *(const float2*)&P[(size_t)s * 524288 + m * 512 + n];
    s0 += v.x; s1 += v.y;
  }
  const float x0 = fmaxf(s0 + bias[n], 0.f);
  const float x1 = fmaxf(s1 + bias[n + 1], 0.f);
  const u16 h0 = f2bf(x0), h1 = f2bf(x1);
  const float l0 = x0 - bf2f(h0), l1 = x1 - bf2f(h1);
  const u32 hh = (u32)h0 | ((u32)h1 << 16);
  const u32 ll = (u32)f2bf(l0) | ((u32)f2bf(l1) << 16);
  const size_t base = (size_t)m * 1536 + n;
  *(u32*)&Ap2[base] = hh;
  *(u32*)&Ap2[base + 512] = hh;
  *(u32*)&Ap2[base + 1024] = ll;
}

// MLP2: sum 6 partials + bias, relu -> fp32 out
__global__ __launch_bounds__(256)
void combine_mlp2(const float* __restrict__ P, const float* __restrict__ bias,
                  float* __restrict__ out) {
  const int idx = blockIdx.x * 256 + threadIdx.x;   // 131072 = 1024*512/4
  const int m = idx >> 7;
  const int n = (idx & 127) * 4;
  float4 s = {0.f, 0.f, 0.f, 0.f};
#pragma unroll
  for (int t = 0; t < 6; ++t) {
    const float4 v = *(const float4*)&P[(size_t)t * 524288 + m * 512 + n];
    s.x += v.x; s.y += v.y; s.z += v.z; s.w += v.w;
  }
  const float4 b = *(const float4*)&bias[n];
  float4 o;
  o.x = fmaxf(s.x + b.x, 0.f);
  o.y = fmaxf(s.y + b.y, 0.f);
  o.z = fmaxf(s.z + b.z, 0.f);
  o.w = fmaxf(s.w + b.w, 0.f);
  *(float4*)&out[(size_t)m * 512 + n] = o;
}

// ---------------------------------------------------------------------------
extern "C" void kernel_launch(void* const* d_in, const int* in_sizes, int n_in,
                              void* d_out, int out_size, void* d_ws, size_t ws_size,
                              hipStream_t stream) {
  const float* gcn_inputs = (const float*)d_in[0];
  // d_in[1] = word_seq_len: unused by the reference
  const float* adj = (const float*)d_in[2];
  const int* lab = (const int*)d_in[3];
  const float* w_params = (const float*)d_in[4];
  const float* w0 = (const float*)d_in[5];
  const float* b0 = (const float*)d_in[6];
  const float* w1 = (const float*)d_in[7];
  const float* b1 = (const float*)d_in[8];
  float* out = (float*)d_out;

  // workspace layout (bytes):
  //   Wbf  [0,        25165824)  : 48*512*512 bf16
  //     P (split-K partials, <=12MB) aliases Wbf (dead after GEMM2)
  //   T    [25165824, 75497472)  : 1024 x 24576 bf16
  //     Bp1 = T+0      (512x1024 bf16)  } written AFTER last T read
  //     Bp2 = T+1MB    (512x1536 bf16)  }
  //   Ha   [75497472, +1MB) : 1024x512 bf16
  //   Hb   [76546048, +1MB) : 1024x512 bf16
  //   Ap1  [77594624, +2MB) : 1024x1024 bf16 (agg#2 DUP output)
  //   Ap2  [79691776, +3MB) : 1024x1536 bf16 (MLP1 hi/hi/lo output)
  char* ws = (char*)d_ws;
  u16* Wbf = (u16*)ws;
  float* P = (float*)ws;                      // aliases Wbf (dead by then)
  u16* T = (u16*)(ws + 25165824);
  u16* Bp1 = T;
  u16* Bp2 = (u16*)(ws + 25165824 + (1 << 20));
  u16* Ha = (u16*)(ws + 75497472);
  u16* Hb = (u16*)(ws + 76546048);
  u16* Ap1 = (u16*)(ws + 77594624);
  u16* Ap2 = (u16*)(ws + 79691776);

  cvt_f32_bf16<<<2048, 256, 0, stream>>>(w_params, Wbf, (48 * 512 * 512) / 4);
  cvt_f32_bf16<<<512, 256, 0, stream>>>(gcn_inputs, Ha, (8 * 128 * 512) / 4);

  // big einsum GEMM: M=1024, N=24576, K=512 -> 1536 blocks, XCD band map
  // GCN layer 1
  gemm_nt_bf16<0><<<1536, 256, 0, stream>>>(Ha, Wbf, T, 24576, 512, 512);
  gcn_agg<false><<<1024, 256, 0, stream>>>(T, adj, lab, Hb);
  // GCN layer 2
  gemm_nt_bf16<0><<<1536, 256, 0, stream>>>(Hb, Wbf, T, 24576, 512, 512);
  gcn_agg<true><<<1024, 256, 0, stream>>>(T, adj, lab, Ap1);   // -> A'=[H,H]

  // MLP weight hi/lo prep (T region dead now; Bp1/Bp2 alias it)
  prep_mlp_w<<<2048, 256, 0, stream>>>(w0, w1, Bp1, Bp2);

  // MLP layer 1: X1 = relu(Ha@W0^T+b0); split-K 4x256 -> 128 blocks
  dim3 g1(512 / BN, 1024 / BM, 4);
  gemm_nt_bf16<1><<<g1, 256, 0, stream>>>(Ap1, Bp1, P, 512, 1024, 256);
  combine_mlp1<<<1024, 256, 0, stream>>>(P, b0, Ap2);
  // MLP layer 2: out = relu(X1@W1^T+b1); split-K 6x256 -> 192 blocks
  dim3 g2(512 / BN, 1024 / BM, 6);
  gemm_nt_bf16<1><<<g2, 256, 0, stream>>>(Ap2, Bp2, P, 512, 1536, 256);
  combine_mlp2<<<512, 256, 0, stream>>>(P, b1, out);
}